// Round 1
// baseline (13871.062 us; speedup 1.0000x reference)
//
#include <hip/hip_runtime.h>
#include <hip/hip_bf16.h>
#include <hip/hip_fp16.h>
#include <stdint.h>
#include <type_traits>

// Problem constants
#define B_ 64
#define T_ 1024
#define I_ 256
#define H_ 512
#define G3_ 1536
#define O_ 256

typedef __attribute__((ext_vector_type(4))) float floatx4;
typedef __attribute__((ext_vector_type(8))) short short8;
typedef __attribute__((ext_vector_type(2))) _Float16 half2v;

// ---------------------------------------------------------------------------
// helpers
// ---------------------------------------------------------------------------
static __device__ __forceinline__ float fdot2f(uint32_t a, uint32_t b, float c) {
#if __has_builtin(__builtin_amdgcn_fdot2)
  return __builtin_amdgcn_fdot2(__builtin_bit_cast(half2v, a),
                                __builtin_bit_cast(half2v, b), c, false);
#else
  __half2 ha = __builtin_bit_cast(__half2, a);
  __half2 hb = __builtin_bit_cast(__half2, b);
  float2 fa = __half22float2(ha), fb = __half22float2(hb);
  return c + fa.x * fb.x + fa.y * fb.y;
#endif
}

static __device__ __forceinline__ float sigmoid_f(float x) {
  float e = __expf(-fabsf(x));
  float a = 1.f / (1.f + e);
  return x >= 0.f ? a : 1.f - a;
}
static __device__ __forceinline__ float tanh_f(float x) {
  float e = __expf(-2.f * fabsf(x));
  float a = (1.f - e) / (1.f + e);
  return x >= 0.f ? a : -a;
}

// ---------------------------------------------------------------------------
// init: pack W_hh -> fp16 register layout, combined biases, zero flags/hstate
// wpack dword index: j + 128*g + 384*kk + 24576*s + 98304*c + 393216*l
//   value = fp16x2 of W_hh_l[row = g*512 + c*128 + j][k = s*128 + 2*kk .. +1]
// ---------------------------------------------------------------------------
__global__ void init_kernel(const float* __restrict__ Whh0, const float* __restrict__ Whh1,
                            const float* __restrict__ bih0, const float* __restrict__ bhh0,
                            const float* __restrict__ bih1, const float* __restrict__ bhh1,
                            uint32_t* __restrict__ wpack, float* __restrict__ biasv,
                            uint32_t* __restrict__ flags, uint32_t* __restrict__ hstate) {
  int idx = blockIdx.x * 256 + threadIdx.x;
  if (idx < 786432) {
    int l = idx / 393216, rem = idx % 393216;
    int j = rem & 127;
    int g = (rem >> 7) % 3;
    int kk = (rem / 384) & 63;
    int s = (rem / 24576) & 3;
    int c = rem / 98304;
    const float* W = l ? Whh1 : Whh0;
    int row = g * 512 + c * 128 + j;
    int k = s * 128 + kk * 2;
    uint32_t lo = __half_as_ushort(__float2half(W[(size_t)row * 512 + k]));
    uint32_t hi = __half_as_ushort(__float2half(W[(size_t)row * 512 + k + 1]));
    wpack[idx] = lo | (hi << 16);
  }
  int i2 = idx - 786432;
  if (i2 >= 0 && i2 < 3072) {
    int l = i2 / 1536, n = i2 % 1536;
    const float* bi = l ? bih1 : bih0;
    const float* bh = l ? bhh1 : bhh0;
    // r,z rows: fold b_ih + b_hh; n rows: b_ih only (b_hh_n is inside r*(.))
    biasv[i2] = bi[n] + (n < 1024 ? bh[n] : 0.f);
  }
  int i3 = idx - (786432 + 3072);
  if (i3 >= 0 && i3 < 131072) flags[i3] = 0u;
  int i4 = idx - (786432 + 3072 + 131072);
  if (i4 >= 0 && i4 < 32768) hstate[i4] = 0u;
}

// ---------------------------------------------------------------------------
// GEMM: C[M,N] = A[M,K] * Bw[N,K]^T + bias, bf16 MFMA 16x16x32.
// A-row mapping handles [B,T,*] chunking: global row = (m>>tcs)*1024 + t0 + (m & (Tc-1)).
// TA in {float, __hip_bfloat16}; TC in {__half, float}.
// ---------------------------------------------------------------------------
template <typename TA, typename TC>
__global__ __launch_bounds__(256, 2) void gemm_bt(
    const TA* __restrict__ A, const float* __restrict__ Bw,
    const float* __restrict__ bias, TC* __restrict__ C,
    int K, int lda, int ldc, int tcshift, int t0) {
  __shared__ unsigned short As[128 * 40];  // padded stride 40 halves = 80B
  __shared__ unsigned short Bs[128 * 40];
  const int tid = threadIdx.x;
  const int bm = blockIdx.x, bn = blockIdx.y;
  const int r = tid >> 1, hf = tid & 1;

  const int m = bm * 128 + r;
  const long arow = ((long)(m >> tcshift) << 10) + t0 + (m & ((1 << tcshift) - 1));
  const TA* ap = A + arow * (long)lda + hf * 16;
  const int n = bn * 128 + r;
  const float* bp = Bw + (long)n * K + hf * 16;

  const int wid = tid >> 6, lane = tid & 63;
  const int wm = (wid >> 1) * 64, wn = (wid & 1) * 64;
  const int m16 = lane & 15, quad = lane >> 4;

  floatx4 acc[4][4];
#pragma unroll
  for (int i = 0; i < 4; ++i)
#pragma unroll
    for (int j = 0; j < 4; ++j) acc[i][j] = 0.f;

  for (int k0 = 0; k0 < K; k0 += 32) {
    unsigned short ta[16], tb[16];
    if constexpr (std::is_same<TA, float>::value) {
      const float4* p = (const float4*)(ap + k0);
#pragma unroll
      for (int q = 0; q < 4; ++q) {
        float4 v = p[q];
        ta[q * 4 + 0] = __builtin_bit_cast(unsigned short, __float2bfloat16(v.x));
        ta[q * 4 + 1] = __builtin_bit_cast(unsigned short, __float2bfloat16(v.y));
        ta[q * 4 + 2] = __builtin_bit_cast(unsigned short, __float2bfloat16(v.z));
        ta[q * 4 + 3] = __builtin_bit_cast(unsigned short, __float2bfloat16(v.w));
      }
    } else {
      const uint4* p = (const uint4*)(ap + k0);
      *(uint4*)&ta[0] = p[0];
      *(uint4*)&ta[8] = p[1];
    }
    {
      const float4* p = (const float4*)(bp + k0);
#pragma unroll
      for (int q = 0; q < 4; ++q) {
        float4 v = p[q];
        tb[q * 4 + 0] = __builtin_bit_cast(unsigned short, __float2bfloat16(v.x));
        tb[q * 4 + 1] = __builtin_bit_cast(unsigned short, __float2bfloat16(v.y));
        tb[q * 4 + 2] = __builtin_bit_cast(unsigned short, __float2bfloat16(v.z));
        tb[q * 4 + 3] = __builtin_bit_cast(unsigned short, __float2bfloat16(v.w));
      }
    }
    *(uint4*)&As[r * 40 + hf * 16] = *(uint4*)&ta[0];
    *(uint4*)&As[r * 40 + hf * 16 + 8] = *(uint4*)&ta[8];
    *(uint4*)&Bs[r * 40 + hf * 16] = *(uint4*)&tb[0];
    *(uint4*)&Bs[r * 40 + hf * 16 + 8] = *(uint4*)&tb[8];
    __syncthreads();
    short8 af[4], bfr[4];
#pragma unroll
    for (int mt = 0; mt < 4; ++mt)
      af[mt] = *(const short8*)&As[(wm + mt * 16 + m16) * 40 + quad * 8];
#pragma unroll
    for (int nt = 0; nt < 4; ++nt)
      bfr[nt] = *(const short8*)&Bs[(wn + nt * 16 + m16) * 40 + quad * 8];
#pragma unroll
    for (int mt = 0; mt < 4; ++mt)
#pragma unroll
      for (int nt = 0; nt < 4; ++nt)
        acc[mt][nt] = __builtin_amdgcn_mfma_f32_16x16x32_bf16(af[mt], bfr[nt],
                                                              acc[mt][nt], 0, 0, 0);
    __syncthreads();
  }
  // epilogue: D row (m, from A) = quad*4+reg, D col (n, from B) = lane&15
#pragma unroll
  for (int mt = 0; mt < 4; ++mt)
#pragma unroll
    for (int nt = 0; nt < 4; ++nt)
#pragma unroll
      for (int rr = 0; rr < 4; ++rr) {
        int grow = bm * 128 + wm + mt * 16 + quad * 4 + rr;
        int gcol = bn * 128 + wn + nt * 16 + m16;
        float v = acc[mt][nt][rr];
        if (bias) v += bias[gcol];
        if constexpr (std::is_same<TC, float>::value)
          C[(long)grow * ldc + gcol] = v;
        else
          C[(long)grow * ldc + gcol] = __float2half(v);
      }
}

// ---------------------------------------------------------------------------
// GRU recurrence: 256 WGs (one per CU), WG (b,c) owns batch b, h-chunk c.
// 512 threads: thread (j = tid&127, s = tid>>7) holds W_hh rows {r,z,n} for
// h-index jp=c*128+j over k in [128s,128s+128) as 192 packed fp16x2 VGPRs.
// Per step: dot2 partials -> LDS reduce -> gates -> h chunk to global hbuf
// (parity double-buffered, agent atomics) -> flag arrive+spin (4 WGs) -> reload.
// ---------------------------------------------------------------------------
__global__ __launch_bounds__(512, 2) void gru_rec(
    const uint32_t* __restrict__ wpack, const __half* __restrict__ xg,
    const float* __restrict__ bhh, uint32_t* __restrict__ hstate,
    __hip_bfloat16* __restrict__ out, uint32_t* __restrict__ hbuf,
    uint32_t* __restrict__ flags, float* __restrict__ hid_out, int t0, int Tc) {
  const int tid = threadIdx.x;
  const int s = tid >> 7;
  const int j = tid & 127;
  const int b = blockIdx.x >> 2;
  const int c = blockIdx.x & 3;
  const int jp = c * 128 + j;

  __shared__ uint32_t hds[256];      // full h as fp16x2
  __shared__ float part[3][512];

  uint32_t w[192];
  {
    const uint32_t* wp = wpack + (size_t)(c * 4 + s) * 24576 + j;
#pragma unroll
    for (int i = 0; i < 192; ++i) w[i] = wp[(size_t)i * 128];
  }
  const float bn_bias = bhh[1024 + jp];

  if (tid < 256) hds[tid] = hstate[b * 256 + tid];
  __syncthreads();

  for (int tt = 0; tt < Tc; ++tt) {
    const int t = t0 + tt;
    float xr = 0.f, xz = 0.f, xn = 0.f;
    if (tid < 128) {  // prefetch x-gates; latency hidden behind dots
      const __half* xp = xg + ((size_t)b * Tc + tt) * 1536;
      xr = __half2float(xp[jp]);
      xz = __half2float(xp[512 + jp]);
      xn = __half2float(xp[1024 + jp]);
    }
    float ar = 0.f, az = 0.f, an = 0.f;
    const int hb = s * 64;
#pragma unroll
    for (int kk = 0; kk < 64; ++kk) {
      uint32_t u = hds[hb + kk];  // wave-uniform -> LDS broadcast
      ar = fdot2f(w[kk * 3 + 0], u, ar);
      az = fdot2f(w[kk * 3 + 1], u, az);
      an = fdot2f(w[kk * 3 + 2], u, an);
    }
    part[0][tid] = ar;
    part[1][tid] = az;
    part[2][tid] = an;
    __syncthreads();
    if (tid < 128) {
      float hr = part[0][tid] + part[0][tid + 128] + part[0][tid + 256] + part[0][tid + 384];
      float hz = part[1][tid] + part[1][tid + 128] + part[1][tid + 256] + part[1][tid + 384];
      float hn = part[2][tid] + part[2][tid + 128] + part[2][tid + 256] + part[2][tid + 384] + bn_bias;
      float rg = sigmoid_f(xr + hr);
      float zg = sigmoid_f(xz + hz);
      float ng = tanh_f(xn + rg * hn);
      float hold = __half2float(((const __half*)hds)[jp]);
      float hnew = (1.f - zg) * ng + zg * hold;
      ((__half*)hds)[jp] = __float2half(hnew);
      out[((size_t)b * 1024 + t) * 512 + jp] = __float2bfloat16(hnew);
      if (t == 1023) hid_out[b * 512 + jp] = hnew;
    }
    __syncthreads();
    if (tid < 64) {
      uint32_t v = hds[c * 64 + tid];
      __hip_atomic_store(&hbuf[((size_t)(t & 1) * 64 + b) * 256 + c * 64 + tid], v,
                         __ATOMIC_RELAXED, __HIP_MEMORY_SCOPE_AGENT);
    }
    __syncthreads();  // drains vmcnt: h stores complete before arrive
    if (tid == 0) {
      __hip_atomic_fetch_add(&flags[b * 1024 + t], 1u, __ATOMIC_RELEASE,
                             __HIP_MEMORY_SCOPE_AGENT);
      while (__hip_atomic_load(&flags[b * 1024 + t], __ATOMIC_ACQUIRE,
                               __HIP_MEMORY_SCOPE_AGENT) < 4u) {
        __builtin_amdgcn_s_sleep(1);
      }
    }
    __syncthreads();
    if (tid < 256) {
      hds[tid] = __hip_atomic_load(&hbuf[((size_t)(t & 1) * 64 + b) * 256 + tid],
                                   __ATOMIC_RELAXED, __HIP_MEMORY_SCOPE_AGENT);
    }
    __syncthreads();
  }
  if (tid < 256) hstate[b * 256 + tid] = hds[tid];
}

// ---------------------------------------------------------------------------
extern "C" void kernel_launch(void* const* d_in, const int* in_sizes, int n_in,
                              void* d_out, int out_size, void* d_ws, size_t ws_size,
                              hipStream_t stream) {
  const float* x = (const float*)d_in[0];
  const float* W_ih0 = (const float*)d_in[1];
  const float* W_hh0 = (const float*)d_in[2];
  const float* b_ih0 = (const float*)d_in[3];
  const float* b_hh0 = (const float*)d_in[4];
  const float* W_ih1 = (const float*)d_in[5];
  const float* W_hh1 = (const float*)d_in[6];
  const float* b_ih1 = (const float*)d_in[7];
  const float* b_hh1 = (const float*)d_in[8];
  const float* fc_w = (const float*)d_in[9];
  const float* fc_b = (const float*)d_in[10];
  float* out = (float*)d_out;

  char* p = (char*)d_ws;
  size_t off = 0;
  auto alloc = [&](size_t bytes) -> void* {
    void* r = p + off;
    off = (off + bytes + 255) & ~(size_t)255;
    return r;
  };
  uint32_t* wpack = (uint32_t*)alloc((size_t)786432 * 4);
  float* biasv = (float*)alloc((size_t)3072 * 4);
  uint32_t* flags = (uint32_t*)alloc((size_t)131072 * 4);
  uint32_t* hstate = (uint32_t*)alloc((size_t)32768 * 4);
  uint32_t* hbuf = (uint32_t*)alloc((size_t)2 * 64 * 256 * 4);
  __hip_bfloat16* out0 = (__hip_bfloat16*)alloc((size_t)B_ * T_ * H_ * 2);
  __hip_bfloat16* out1 = (__hip_bfloat16*)alloc((size_t)B_ * T_ * H_ * 2);
  size_t remain = ws_size > off ? ws_size - off : 0;
  int Tc = 1024;
  while (Tc > 2 && (size_t)B_ * Tc * G3_ * 2 > remain) Tc >>= 1;
  __half* xg = (__half*)(p + off);
  int tcs = __builtin_ctz(Tc);

  init_kernel<<<3724, 256, 0, stream>>>(W_hh0, W_hh1, b_ih0, b_hh0, b_ih1, b_hh1,
                                        wpack, biasv, flags, hstate);

  for (int l = 0; l < 2; ++l) {
    const float* Wih = l ? W_ih1 : W_ih0;
    const float* bhh = l ? b_hh1 : b_hh0;
    const int K = l ? 512 : 256;
    for (int t0 = 0; t0 < 1024; t0 += Tc) {
      const int M = B_ * Tc;
      dim3 gg(M / 128, G3_ / 128);
      if (l == 0)
        gemm_bt<float, __half><<<gg, 256, 0, stream>>>(x, Wih, biasv, xg, K, I_,
                                                       G3_, tcs, t0);
      else
        gemm_bt<__hip_bfloat16, __half><<<gg, 256, 0, stream>>>(
            out0, Wih, biasv + 1536, xg, K, H_, G3_, tcs, t0);
      gru_rec<<<256, 512, 0, stream>>>(
          wpack + (size_t)l * 393216, xg, bhh, hstate + (size_t)l * 16384,
          l ? out1 : out0, hbuf, flags + (size_t)l * 65536,
          out + 16777216 + l * 32768, t0, Tc);
    }
  }
  // FC: [65536,512] x fc_w[256,512]^T + fc_b -> d_out fp32
  dim3 gf(65536 / 128, O_ / 128);
  gemm_bt<__hip_bfloat16, float><<<gf, 256, 0, stream>>>(out1, fc_w, fc_b, out,
                                                         H_, H_, O_, 10, 0);
}